// Round 2
// baseline (745.742 us; speedup 1.0000x reference)
//
#include <hip/hip_runtime.h>
#include <math.h>

namespace {

constexpr float kC1 = 1e-4f;   // (0.01)^2
constexpr float kC2 = 9e-4f;   // (0.03)^2

// Normalized 1D Gaussian half-kernel. Truncation tail < 2e-6 relative.
template<int R>
__device__ __forceinline__ void make_w(float sigma, float (&w)[R + 1]) {
  const float inv2s2 = 1.0f / (2.0f * sigma * sigma);
#pragma unroll
  for (int k = 0; k <= R; ++k) w[k] = expf(-(float)(k * k) * inv2s2);
  float s = w[0];
#pragma unroll
  for (int k = 1; k <= R; ++k) s += 2.0f * w[k];
  const float inv = 1.0f / s;
#pragma unroll
  for (int k = 0; k <= R; ++k) w[k] *= inv;
}

// LDS buffers (all float, XOR-swizzled on float4 groups by row&7):
//  sS/sD : logical [64 rows][64 cols], phys idx = row*64 + ((g ^ (row&7))<<2)+u
//  hb0   : pairs (s,d)   logical [64 rows][32 cols][2]  (4096 floats)
//  hb1   : pairs (s2,d2) same layout
//  hbl   : |d|           logical [64 rows][32 cols]     (2048 floats)

// Fused horizontal pass. MODE: 0 = 4 quantities, 1 = 5 (adds |d|), 2 = |d| only.
// 512 entries (64 halo rows x 8 col-groups of 4), 2 entries/thread.
// Window is STREAMED: one float4 of s and d at a time -> FMAs -> discard.
template<int R, int MODE>
__device__ __forceinline__ void hpass(const float* __restrict__ sSp,
                                      const float* __restrict__ sDp,
                                      float* __restrict__ h0, float* __restrict__ h1,
                                      float* __restrict__ hl,
                                      const float (&w)[R + 1], int t) {
  constexpr int QS = (16 - R) & ~3;              // window start rel. to c0 (floats)
  constexpr int NG = ((19 + R - QS) >> 2) + 1;   // float4 groups in window
#pragma unroll 1
  for (int e = 0; e < 2; ++e) {
    const int entry = t + (e << 8);
    const int row = entry >> 3;
    const int cg = entry & 7;          // output col group (cols 4*cg .. 4*cg+3)
    const int rx = row & 7;
    const int rowbase = row << 6;
    const int g0 = cg + (QS >> 2);
    float as[4] = {0.f, 0.f, 0.f, 0.f}, ad[4] = {0.f, 0.f, 0.f, 0.f};
    float as2[4] = {0.f, 0.f, 0.f, 0.f}, ad2[4] = {0.f, 0.f, 0.f, 0.f};
    float al[4] = {0.f, 0.f, 0.f, 0.f};
#pragma unroll
    for (int j = 0; j < NG; ++j) {
      const int off = rowbase + (((g0 + j) ^ rx) << 2);
      float4 s4 = make_float4(0.f, 0.f, 0.f, 0.f);
      if (MODE != 2) s4 = *reinterpret_cast<const float4*>(&sSp[off]);
      const float4 d4 = *reinterpret_cast<const float4*>(&sDp[off]);
      const float* sp = reinterpret_cast<const float*>(&s4);
      const float* dp = reinterpret_cast<const float*>(&d4);
#pragma unroll
      for (int u = 0; u < 4; ++u) {
        const int kb = QS + 4 * j + u - 16;   // compile-time after unroll
        const float sv = sp[u], dv = dp[u];
        float s2 = 0.f, d2 = 0.f, av = 0.f;
        if (MODE != 2) { s2 = sv * sv; d2 = dv * dv; }
        if (MODE != 0) av = fabsf(dv);
#pragma unroll
        for (int o = 0; o < 4; ++o) {
          const int k = kb - o;
          if (k >= -R && k <= R) {
            const float wk = w[(k < 0) ? -k : k];
            if (MODE != 2) {
              as[o] += wk * sv; ad[o] += wk * dv;
              as2[o] += wk * s2; ad2[o] += wk * d2;
            }
            if (MODE != 0) al[o] += wk * av;
          }
        }
      }
    }
    if (MODE != 2) {
      const int ga = ((cg << 1) ^ rx) << 2;
      const int gb = (((cg << 1) | 1) ^ rx) << 2;
      *reinterpret_cast<float4*>(&h0[rowbase + ga]) = make_float4(as[0], ad[0], as[1], ad[1]);
      *reinterpret_cast<float4*>(&h0[rowbase + gb]) = make_float4(as[2], ad[2], as[3], ad[3]);
      *reinterpret_cast<float4*>(&h1[rowbase + ga]) = make_float4(as2[0], ad2[0], as2[1], ad2[1]);
      *reinterpret_cast<float4*>(&h1[rowbase + gb]) = make_float4(as2[2], ad2[2], as2[3], ad2[3]);
    }
    if (MODE != 0) {
      *reinterpret_cast<float4*>(&hl[(row << 5) + ((cg ^ rx) << 2)]) =
          make_float4(al[0], al[1], al[2], al[3]);
    }
  }
}

// Vertical pass: thread owns column vc, output rows vr0..vr0+3.
// Pair buffers read as float2 (b64); column reads are swizzle-spread.
template<int R, int MODE>
__device__ __forceinline__ void vpass(const float* __restrict__ h0,
                                      const float* __restrict__ h1,
                                      const float* __restrict__ hl,
                                      const float (&w)[R + 1], int vc, int vr0,
                                      float (&os)[4], float (&od)[4],
                                      float (&os2)[4], float (&od2)[4], float (&ol)[4]) {
#pragma unroll
  for (int i = 0; i < 4; ++i) { os[i] = od[i] = os2[i] = od2[i] = ol[i] = 0.f; }
#pragma unroll
  for (int jj = 0; jj < 2 * R + 4; ++jj) {
    const int r = vr0 + 16 - R + jj;
    const int rx = r & 7;
    float2 v01 = make_float2(0.f, 0.f), v23 = make_float2(0.f, 0.f);
    float vl = 0.f;
    if (MODE != 2) {
      const int off = (r << 6) + (((vc >> 1) ^ rx) << 2) + ((vc & 1) << 1);
      v01 = *reinterpret_cast<const float2*>(&h0[off]);
      v23 = *reinterpret_cast<const float2*>(&h1[off]);
    }
    if (MODE != 0) vl = hl[(r << 5) + (((vc >> 2) ^ rx) << 2) + (vc & 3)];
#pragma unroll
    for (int i = 0; i < 4; ++i) {
      const int k = jj - R - i;
      if (k >= -R && k <= R) {
        const float wk = w[(k < 0) ? -k : k];
        if (MODE != 2) {
          os[i] += wk * v01.x; od[i] += wk * v01.y;
          os2[i] += wk * v23.x; od2[i] += wk * v23.y;
        }
        if (MODE != 0) ol[i] += wk * vl;
      }
    }
  }
}

template<int R, int MODE>
__device__ __forceinline__ void run_sweep(float sigma, int mult, bool doLM,
    const float* sSp, const float* sDp, float* h0, float* h1, float* hl,
    int t, int vc, int vr0, float (&PI)[4], float (&lM)[4], float (&l1s)[4]) {
  float w[R + 1];
  make_w<R>(sigma, w);
  __syncthreads();             // prior vpass reads of hb done; tile loads visible
  hpass<R, MODE>(sSp, sDp, h0, h1, hl, w, t);
  __syncthreads();
  float os[4], od[4], os2[4], od2[4], ol[4];
  vpass<R, MODE>(h0, h1, hl, w, vc, vr0, os, od, os2, od2, ol);
  if constexpr (MODE != 2) {
#pragma unroll
    for (int i = 0; i < 4; ++i) {
      const float mus = os[i], mud = od[i];
      const float vs = os2[i] - mus * mus;     // Var(x+y)
      const float vd = od2[i] - mud * mud;     // Var(x-y)
      // 2*sigma_xy = (vs-vd)/2 ; sigma_x^2+sigma_y^2 = (vs+vd)/2
      const float cs = (0.5f * (vs - vd) + kC2) / (0.5f * (vs + vd) + kC2);
      float p = cs;
      if (mult > 1) p *= cs;
      if (mult > 2) p *= cs;
      PI[i] *= p;
      if (doLM) {
        const float a2 = mus * mus, b2 = mud * mud;
        // 2*mux*muy = (a2-b2)/2 ; mux^2+muy^2 = (a2+b2)/2
        const float lc = (0.5f * (a2 - b2) + kC1) / (0.5f * (a2 + b2) + kC1);
        lM[i] = lc * lc * lc;
      }
      if (MODE == 1) l1s[i] += ol[i];
    }
  } else {
#pragma unroll
    for (int i = 0; i < 4; ++i) l1s[i] += ol[i];
  }
}

__device__ __forceinline__ void load_tile(const float* __restrict__ p1,
                                          const float* __restrict__ p2,
                                          float* __restrict__ sSp, float* __restrict__ sDp,
                                          int t, int gx0, int gy0) {
#pragma unroll 1
  for (int e = 0; e < 4; ++e) {
    const int g = t + (e << 8);      // 0..1023 float4 groups
    const int ly = g >> 4, lg = g & 15;
    const int gy = gy0 + ly;
    const int gx = gx0 + (lg << 2);
    float4 a = make_float4(0.f, 0.f, 0.f, 0.f);
    float4 b = make_float4(0.f, 0.f, 0.f, 0.f);
    if (gy >= 0 && gy < 512) {
      if (gx >= 0 && gx + 3 < 512) {
        a = *reinterpret_cast<const float4*>(&p1[(gy << 9) + gx]);
        b = *reinterpret_cast<const float4*>(&p2[(gy << 9) + gx]);
      } else {
        float* ap = reinterpret_cast<float*>(&a);
        float* bp = reinterpret_cast<float*>(&b);
#pragma unroll
        for (int u = 0; u < 4; ++u) {
          const int x = gx + u;
          if (x >= 0 && x < 512) { ap[u] = p1[(gy << 9) + x]; bp[u] = p2[(gy << 9) + x]; }
        }
      }
    }
    float4 s, d;
    s.x = a.x + b.x; s.y = a.y + b.y; s.z = a.z + b.z; s.w = a.w + b.w;
    d.x = a.x - b.x; d.y = a.y - b.y; d.z = a.z - b.z; d.w = a.w - b.w;
    const int off = (ly << 6) + ((lg ^ (ly & 7)) << 2);
    *reinterpret_cast<float4*>(&sSp[off]) = s;
    *reinterpret_cast<float4*>(&sDp[off]) = d;
  }
}

}  // namespace

extern "C" __global__ __launch_bounds__(256, 2) void msssim_main(
    const float* __restrict__ img1, const float* __restrict__ img2,
    float* __restrict__ partial) {
  __shared__ __align__(16) float sS[4096];
  __shared__ __align__(16) float sD[4096];
  __shared__ __align__(16) float hb0[4096];
  __shared__ __align__(16) float hb1[4096];
  __shared__ __align__(16) float hbl[2048];

  const int t = threadIdx.x;
  const int b = blockIdx.z;
  const int gx0 = (int)blockIdx.x * 32 - 16;
  const int gy0 = (int)blockIdx.y * 32 - 16;
  const int vc = t & 31;
  const int vr0 = (t >> 5) << 2;

  float PI[4] = {1.f, 1.f, 1.f, 1.f};
  float lM[4] = {0.f, 0.f, 0.f, 0.f};
  float l1s[4] = {0.f, 0.f, 0.f, 0.f};

  const float* c0a = img1 + (((size_t)b * 3 + 0) << 18);
  const float* c0b = img2 + (((size_t)b * 3 + 0) << 18);
  const float* c1a = img1 + (((size_t)b * 3 + 1) << 18);
  const float* c1b = img2 + (((size_t)b * 3 + 1) << 18);
  const float* c2a = img1 + (((size_t)b * 3 + 2) << 18);
  const float* c2b = img2 + (((size_t)b * 3 + 2) << 18);

  // Channel 0: cs(s0.5)^3, cs(s1)^2, L1 blur (s8)
  load_tile(c0a, c0b, sS, sD, t, gx0, gy0);
  run_sweep<2, 0>(0.5f, 3, false, sS, sD, hb0, hb1, hbl, t, vc, vr0, PI, lM, l1s);
  run_sweep<5, 0>(1.0f, 2, false, sS, sD, hb0, hb1, hbl, t, vc, vr0, PI, lM, l1s);
  run_sweep<16, 2>(8.0f, 0, false, sS, sD, hb0, hb1, hbl, t, vc, vr0, PI, lM, l1s);

  // Channel 1: cs(s1)^1, cs(s2)^3, cs(s4)^1, L1 blur (s8)
  load_tile(c1a, c1b, sS, sD, t, gx0, gy0);
  run_sweep<5, 0>(1.0f, 1, false, sS, sD, hb0, hb1, hbl, t, vc, vr0, PI, lM, l1s);
  run_sweep<11, 0>(2.0f, 3, false, sS, sD, hb0, hb1, hbl, t, vc, vr0, PI, lM, l1s);
  run_sweep<16, 0>(4.0f, 1, false, sS, sD, hb0, hb1, hbl, t, vc, vr0, PI, lM, l1s);
  run_sweep<16, 2>(8.0f, 0, false, sS, sD, hb0, hb1, hbl, t, vc, vr0, PI, lM, l1s);

  // Channel 2: cs(s4)^2, cs(s8)^3 + lM + L1 blur (s8) fused
  load_tile(c2a, c2b, sS, sD, t, gx0, gy0);
  run_sweep<16, 0>(4.0f, 2, false, sS, sD, hb0, hb1, hbl, t, vc, vr0, PI, lM, l1s);
  run_sweep<16, 1>(8.0f, 3, true, sS, sD, hb0, hb1, hbl, t, vc, vr0, PI, lM, l1s);

  float s = 0.f;
#pragma unroll
  for (int i = 0; i < 4; ++i)
    s += 0.025f * (1.f - lM[i] * PI[i]) + 0.975f * (l1s[i] * (1.f / 3.f));

#pragma unroll
  for (int off = 32; off >= 1; off >>= 1) s += __shfl_down(s, off, 64);
  __syncthreads();
  if ((t & 63) == 0) hbl[t >> 6] = s;
  __syncthreads();
  if (t == 0) {
    partial[((size_t)blockIdx.z * gridDim.y + blockIdx.y) * gridDim.x + blockIdx.x] =
        hbl[0] + hbl[1] + hbl[2] + hbl[3];
  }
}

extern "C" __global__ __launch_bounds__(256) void msssim_reduce(
    const float* __restrict__ partial, float* __restrict__ out, int n) {
  __shared__ float red[4];
  float s = 0.f;
  for (int i = threadIdx.x; i < n; i += 256) s += partial[i];
#pragma unroll
  for (int off = 32; off >= 1; off >>= 1) s += __shfl_down(s, off, 64);
  if ((threadIdx.x & 63) == 0) red[threadIdx.x >> 6] = s;
  __syncthreads();
  if (threadIdx.x == 0) {
    out[0] = (red[0] + red[1] + red[2] + red[3]) * (200.0f / 2097152.0f);
  }
}

extern "C" void kernel_launch(void* const* d_in, const int* in_sizes, int n_in,
                              void* d_out, int out_size, void* d_ws, size_t ws_size,
                              hipStream_t stream) {
  const float* img1 = (const float*)d_in[0];
  const float* img2 = (const float*)d_in[1];
  float* out = (float*)d_out;
  float* partial = (float*)d_ws;  // 2048 floats

  dim3 grid(16, 16, 8);
  msssim_main<<<grid, dim3(256), 0, stream>>>(img1, img2, partial);
  msssim_reduce<<<1, dim3(256), 0, stream>>>(partial, out, 2048);
}

// Round 3
// 469.519 us; speedup vs baseline: 1.5883x; 1.5883x over previous
//
#include <hip/hip_runtime.h>
#include <math.h>

struct GW { float w[55]; };
// weight table offsets (radius R, count R+1)
constexpr int W05 = 0;   // sigma 0.5, R=2
constexpr int W1  = 3;   // sigma 1,   R=5
constexpr int W2  = 9;   // sigma 2,   R=11
constexpr int W4  = 21;  // sigma 4,   R=16
constexpr int W8  = 38;  // sigma 8,   R=16

namespace {

constexpr float kC1 = 1e-4f;
constexpr float kC2 = 9e-4f;

// LDS layout:
//  sS/sD: [64 rows][64 cols] floats, float4-group g XOR'd by (row&7)
//  hb4  : [<=64 rows][32 cols] float4 (s,d,s2,d2), col XOR'd by (hrow&7)
//  hbl  : aliases hb4: [<=64 rows][32 cols] float, group (col>>2) XOR'd by (hrow&7)

// Horizontal pass. MODE 0: 4 quantities (s,d,s2,d2). MODE 2: |d| only (L1).
// Rows trimmed to NROWS = 32+2R (hrow 0.. maps to halo row hrow+16-R).
template<int R, int WOFF, int MODE>
__device__ __forceinline__ void hpass(const GW& g, const float* __restrict__ sS,
                                      const float* __restrict__ sD,
                                      float* __restrict__ hb, int t) {
  constexpr int NROWS = 32 + 2 * R;
  constexpr int NE = NROWS * 8;
  constexpr int QS = (16 - R) & ~3;
  constexpr int NG = ((19 + R - QS) >> 2) + 1;
#pragma unroll 1
  for (int e = 0; e < 2; ++e) {
    const int entry = t + (e << 8);
    if (entry < NE) {
      const int hrow = entry >> 3;
      const int cg = entry & 7;
      const int srow = hrow + (16 - R);
      const int rx = srow & 7;
      const int rowbase = srow << 6;
      const int g0 = cg + (QS >> 2);
      float a0[4] = {0.f, 0.f, 0.f, 0.f}, a1[4] = {0.f, 0.f, 0.f, 0.f};
      float a2[4] = {0.f, 0.f, 0.f, 0.f}, a3[4] = {0.f, 0.f, 0.f, 0.f};
#pragma unroll
      for (int j = 0; j < NG; ++j) {
        const int off = rowbase + (((g0 + j) ^ rx) << 2);
        float4 s4 = make_float4(0.f, 0.f, 0.f, 0.f);
        if constexpr (MODE == 0) s4 = *reinterpret_cast<const float4*>(&sS[off]);
        const float4 d4 = *reinterpret_cast<const float4*>(&sD[off]);
        const float* sp = reinterpret_cast<const float*>(&s4);
        const float* dp = reinterpret_cast<const float*>(&d4);
#pragma unroll
        for (int u = 0; u < 4; ++u) {
          const int kb = QS + 4 * j + u - 16;
          const float dv = dp[u];
          float sv = 0.f, s2 = 0.f, d2 = 0.f, av = 0.f;
          if constexpr (MODE == 0) { sv = sp[u]; s2 = sv * sv; d2 = dv * dv; }
          else av = fabsf(dv);
#pragma unroll
          for (int o = 0; o < 4; ++o) {
            const int k = kb - o;
            if (k >= -R && k <= R) {
              const float wk = g.w[WOFF + ((k < 0) ? -k : k)];
              if constexpr (MODE == 0) {
                a0[o] += wk * sv; a1[o] += wk * dv;
                a2[o] += wk * s2; a3[o] += wk * d2;
              } else {
                a0[o] += wk * av;
              }
            }
          }
        }
      }
      const int hx = hrow & 7;
      if constexpr (MODE == 0) {
#pragma unroll
        for (int o = 0; o < 4; ++o) {
          const int col = (cg << 2) + o;
          const int phys = ((hrow << 5) + (col ^ hx)) << 2;
          *reinterpret_cast<float4*>(&hb[phys]) = make_float4(a0[o], a1[o], a2[o], a3[o]);
        }
      } else {
        const int phys = (hrow << 5) + ((cg ^ hx) << 2);
        *reinterpret_cast<float4*>(&hb[phys]) = make_float4(a0[0], a0[1], a0[2], a0[3]);
      }
    }
  }
}

// Vertical pass. Thread owns col vc, output rows vr0..vr0+3.
template<int R, int WOFF, int MODE>
__device__ __forceinline__ void vpass(const GW& g, const float* __restrict__ hb,
                                      int vc, int vr0,
                                      float (&o0)[4], float (&o1)[4],
                                      float (&o2)[4], float (&o3)[4]) {
#pragma unroll
  for (int i = 0; i < 4; ++i) { o0[i] = o1[i] = o2[i] = o3[i] = 0.f; }
#pragma unroll
  for (int jj = 0; jj < 2 * R + 4; ++jj) {
    const int r = vr0 + jj;
    const int rx = r & 7;
    float4 v = make_float4(0.f, 0.f, 0.f, 0.f);
    float vl = 0.f;
    if constexpr (MODE == 0)
      v = *reinterpret_cast<const float4*>(&hb[((r << 5) + (vc ^ rx)) << 2]);
    else
      vl = hb[(r << 5) + ((((vc >> 2)) ^ rx) << 2) + (vc & 3)];
#pragma unroll
    for (int i = 0; i < 4; ++i) {
      const int k = jj - i - R;
      if (k >= -R && k <= R) {
        const float wk = g.w[WOFF + ((k < 0) ? -k : k)];
        if constexpr (MODE == 0) {
          o0[i] += wk * v.x; o1[i] += wk * v.y;
          o2[i] += wk * v.z; o3[i] += wk * v.w;
        } else {
          o0[i] += wk * vl;
        }
      }
    }
  }
}

template<int R, int WOFF>
__device__ __forceinline__ void sweep4(const GW& g, int mult, bool doLM,
    const float* sS, const float* sD, float* hb, int t, int vc, int vr0,
    float (&PI)[4], float (&lM)[4]) {
  __syncthreads();
  hpass<R, WOFF, 0>(g, sS, sD, hb, t);
  __syncthreads();
  float os[4], od[4], os2[4], od2[4];
  vpass<R, WOFF, 0>(g, hb, vc, vr0, os, od, os2, od2);
#pragma unroll
  for (int i = 0; i < 4; ++i) {
    const float vs = os2[i] - os[i] * os[i];   // Var(x+y)
    const float vd = od2[i] - od[i] * od[i];   // Var(x-y)
    const float cs = (0.5f * (vs - vd) + kC2) / (0.5f * (vs + vd) + kC2);
    float p = cs;
    if (mult > 1) p *= cs;
    if (mult > 2) p *= cs;
    PI[i] *= p;
    if (doLM) {
      const float sa = os[i] * os[i], sb = od[i] * od[i];
      const float lc = (0.5f * (sa - sb) + kC1) / (0.5f * (sa + sb) + kC1);
      lM[i] = lc * lc * lc;
    }
  }
}

template<int R, int WOFF>
__device__ __forceinline__ void sweepL1(const GW& g,
    const float* sS, const float* sD, float* hb, int t, int vc, int vr0,
    float (&l1s)[4]) {
  __syncthreads();
  hpass<R, WOFF, 2>(g, sS, sD, hb, t);
  __syncthreads();
  float o0[4], o1[4], o2[4], o3[4];
  vpass<R, WOFF, 2>(g, hb, vc, vr0, o0, o1, o2, o3);
#pragma unroll
  for (int i = 0; i < 4; ++i) l1s[i] += o0[i];
}

__device__ __forceinline__ void load_tile(const float* __restrict__ p1,
                                          const float* __restrict__ p2,
                                          float* __restrict__ sS, float* __restrict__ sD,
                                          int t, int gx0, int gy0) {
#pragma unroll 1
  for (int e = 0; e < 4; ++e) {
    const int gidx = t + (e << 8);
    const int ly = gidx >> 4, lg = gidx & 15;
    const int gy = gy0 + ly;
    const int gx = gx0 + (lg << 2);
    float4 a = make_float4(0.f, 0.f, 0.f, 0.f);
    float4 b = make_float4(0.f, 0.f, 0.f, 0.f);
    if (gy >= 0 && gy < 512) {
      if (gx >= 0 && gx + 3 < 512) {
        a = *reinterpret_cast<const float4*>(&p1[(gy << 9) + gx]);
        b = *reinterpret_cast<const float4*>(&p2[(gy << 9) + gx]);
      } else {
        float* ap = reinterpret_cast<float*>(&a);
        float* bp = reinterpret_cast<float*>(&b);
#pragma unroll
        for (int u = 0; u < 4; ++u) {
          const int x = gx + u;
          if (x >= 0 && x < 512) { ap[u] = p1[(gy << 9) + x]; bp[u] = p2[(gy << 9) + x]; }
        }
      }
    }
    float4 s, d;
    s.x = a.x + b.x; s.y = a.y + b.y; s.z = a.z + b.z; s.w = a.w + b.w;
    d.x = a.x - b.x; d.y = a.y - b.y; d.z = a.z - b.z; d.w = a.w - b.w;
    const int off = (ly << 6) + ((lg ^ (ly & 7)) << 2);
    *reinterpret_cast<float4*>(&sS[off]) = s;
    *reinterpret_cast<float4*>(&sD[off]) = d;
  }
}

}  // namespace

extern "C" __global__ __launch_bounds__(256) void msssim_main(
    const float* __restrict__ img1, const float* __restrict__ img2,
    float* __restrict__ partial, GW g) {
  __shared__ __align__(16) float sS[4096];
  __shared__ __align__(16) float sD[4096];
  __shared__ __align__(16) float hb4[8192];   // also aliased as the L1 h-buffer
  __shared__ float red[4];

  const int t = threadIdx.x;

  // XCD-contiguous swizzle: 2048 blocks, 8 XCDs -> XCD k owns batch image k.
  const int bid = (int)blockIdx.x + ((int)blockIdx.y << 4) + ((int)blockIdx.z << 8);
  const int swz = ((bid & 7) << 8) + (bid >> 3);
  const int bx = swz & 15, by = (swz >> 4) & 15, b = swz >> 8;

  const int gx0 = bx * 32 - 16;
  const int gy0 = by * 32 - 16;
  const int vc = t & 31;
  const int vr0 = (t >> 5) << 2;

  float PI[4] = {1.f, 1.f, 1.f, 1.f};
  float lM[4] = {0.f, 0.f, 0.f, 0.f};
  float l1s[4] = {0.f, 0.f, 0.f, 0.f};

  // Channel 0: cs(s0.5)^3 * cs(s1)^2 ; L1 blur s8
  {
    const float* p1 = img1 + (((size_t)b * 3 + 0) << 18);
    const float* p2 = img2 + (((size_t)b * 3 + 0) << 18);
    load_tile(p1, p2, sS, sD, t, gx0, gy0);
    sweep4<2, W05>(g, 3, false, sS, sD, hb4, t, vc, vr0, PI, lM);
    sweep4<5, W1>(g, 2, false, sS, sD, hb4, t, vc, vr0, PI, lM);
    sweepL1<16, W8>(g, sS, sD, hb4, t, vc, vr0, l1s);
  }
  // Channel 1: cs(s1)^1 * cs(s2)^3 * cs(s4)^1 ; L1 blur s8
  {
    const float* p1 = img1 + (((size_t)b * 3 + 1) << 18);
    const float* p2 = img2 + (((size_t)b * 3 + 1) << 18);
    load_tile(p1, p2, sS, sD, t, gx0, gy0);
    sweep4<5, W1>(g, 1, false, sS, sD, hb4, t, vc, vr0, PI, lM);
    sweep4<11, W2>(g, 3, false, sS, sD, hb4, t, vc, vr0, PI, lM);
    sweep4<16, W4>(g, 1, false, sS, sD, hb4, t, vc, vr0, PI, lM);
    sweepL1<16, W8>(g, sS, sD, hb4, t, vc, vr0, l1s);
  }
  // Channel 2: cs(s4)^2 * cs(s8)^3 + lM(s8) ; L1 blur s8
  {
    const float* p1 = img1 + (((size_t)b * 3 + 2) << 18);
    const float* p2 = img2 + (((size_t)b * 3 + 2) << 18);
    load_tile(p1, p2, sS, sD, t, gx0, gy0);
    sweep4<16, W4>(g, 2, false, sS, sD, hb4, t, vc, vr0, PI, lM);
    sweep4<16, W8>(g, 3, true, sS, sD, hb4, t, vc, vr0, PI, lM);
    sweepL1<16, W8>(g, sS, sD, hb4, t, vc, vr0, l1s);
  }

  float s = 0.f;
#pragma unroll
  for (int i = 0; i < 4; ++i)
    s += 0.025f * (1.f - lM[i] * PI[i]) + 0.975f * (l1s[i] * (1.f / 3.f));

#pragma unroll
  for (int off = 32; off >= 1; off >>= 1) s += __shfl_down(s, off, 64);
  if ((t & 63) == 0) red[t >> 6] = s;
  __syncthreads();
  if (t == 0) partial[swz] = red[0] + red[1] + red[2] + red[3];
}

extern "C" __global__ __launch_bounds__(256) void msssim_reduce(
    const float* __restrict__ partial, float* __restrict__ out, int n) {
  __shared__ float red[4];
  float s = 0.f;
  for (int i = threadIdx.x; i < n; i += 256) s += partial[i];
#pragma unroll
  for (int off = 32; off >= 1; off >>= 1) s += __shfl_down(s, off, 64);
  if ((threadIdx.x & 63) == 0) red[threadIdx.x >> 6] = s;
  __syncthreads();
  if (threadIdx.x == 0) {
    out[0] = (red[0] + red[1] + red[2] + red[3]) * (200.0f / 2097152.0f);
  }
}

extern "C" void kernel_launch(void* const* d_in, const int* in_sizes, int n_in,
                              void* d_out, int out_size, void* d_ws, size_t ws_size,
                              hipStream_t stream) {
  const float* img1 = (const float*)d_in[0];
  const float* img2 = (const float*)d_in[1];
  float* out = (float*)d_out;
  float* partial = (float*)d_ws;  // 2048 floats

  // Host-side weight table (pure CPU work; graph-capture safe).
  GW g;
  {
    const double sig[5] = {0.5, 1.0, 2.0, 4.0, 8.0};
    const int R[5] = {2, 5, 11, 16, 16};
    const int off[5] = {W05, W1, W2, W4, W8};
    for (int i = 0; i < 5; ++i) {
      double tmp[17];
      double sum = 0.0;
      for (int k = 0; k <= R[i]; ++k) {
        tmp[k] = exp(-(double)(k * k) / (2.0 * sig[i] * sig[i]));
        sum += (k ? 2.0 : 1.0) * tmp[k];
      }
      for (int k = 0; k <= R[i]; ++k) g.w[off[i] + k] = (float)(tmp[k] / sum);
    }
  }

  dim3 grid(16, 16, 8);
  msssim_main<<<grid, dim3(256), 0, stream>>>(img1, img2, partial, g);
  msssim_reduce<<<1, dim3(256), 0, stream>>>(partial, out, 2048);
}

// Round 4
// 214.279 us; speedup vs baseline: 3.4802x; 2.1912x over previous
//
#include <hip/hip_runtime.h>
#include <math.h>

// Zero-padded symmetric weight tables: per sigma, layout is
// [8 zeros][w[R], ..., w[1], w[0], w[1], ..., w[R]][8 zeros]  (length 2R+17).
// Index m in [0, 2R] holds w[|m-R|] at table offset m+8. The pads absorb all
// out-of-range taps so the tap loops need no conditionals.
struct GW { float w[185]; };
constexpr int W05 = 0;    // sigma 0.5, R=2,  len 21
constexpr int W1  = 21;   // sigma 1,   R=5,  len 27
constexpr int W2  = 48;   // sigma 2,   R=11, len 39
constexpr int W4  = 87;   // sigma 4,   R=16, len 49
constexpr int W8  = 136;  // sigma 8,   R=16, len 49

namespace {

constexpr float kC1 = 1e-4f;
constexpr float kC2 = 9e-4f;

// LDS:
//  sS/sD : [64][64] floats, float4-group g XOR'd by (row&7)  (16 KB each)
//  hb4   : [64 rows][32 slots] float4 (s,d,s2,d2); slot = f(col), f(c)=c^((c>>3)&3)
//          -> h-pass stores and v-pass reads both spread over all 8 bank classes.
//  hbl   : MODE2 reuse of hb4: [64][32] floats, plain layout (conflict-free).

// Horizontal pass, rows trimmed to NROWS=32+2R (hrow h = halo row h+16-R).
// MODE 0: (s,d,s2,d2). MODE 2: |d| only.
template<int R, int WOFF, int MODE>
__device__ __forceinline__ void hpass(const GW& g, const float* __restrict__ sS,
                                      const float* __restrict__ sD,
                                      float* __restrict__ hb, int t) {
  constexpr int NROWS = 32 + 2 * R;
  constexpr int NE = NROWS * 8;
  constexpr int QS = (16 - R) & ~3;
  constexpr int NG = ((19 + R - QS) >> 2) + 1;
#pragma unroll 1
  for (int e = 0; e < 2; ++e) {
    const int entry = t + (e << 8);
    if (entry < NE) {
      const int hrow = entry >> 3;
      const int cg = entry & 7;
      const int srow = hrow + (16 - R);
      const int rx = srow & 7;
      const int rowbase = srow << 6;
      const int g0 = cg + (QS >> 2);
      float a0[4] = {0.f, 0.f, 0.f, 0.f}, a1[4] = {0.f, 0.f, 0.f, 0.f};
      float a2[4] = {0.f, 0.f, 0.f, 0.f}, a3[4] = {0.f, 0.f, 0.f, 0.f};
#pragma unroll 2
      for (int j = 0; j < NG; ++j) {
        const int off = rowbase + (((g0 + j) ^ rx) << 2);
        // weight index for (u,o): wb + u - o  (uniform; pads absorb overflow)
        const int wb = WOFF + 8 + QS - 16 + R + 4 * j;
        float4 s4 = make_float4(0.f, 0.f, 0.f, 0.f);
        if constexpr (MODE == 0) s4 = *reinterpret_cast<const float4*>(&sS[off]);
        const float4 d4 = *reinterpret_cast<const float4*>(&sD[off]);
        const float* sp = reinterpret_cast<const float*>(&s4);
        const float* dp = reinterpret_cast<const float*>(&d4);
#pragma unroll
        for (int u = 0; u < 4; ++u) {
          const float dv = dp[u];
          float sv = 0.f, s2 = 0.f, d2 = 0.f, av = 0.f;
          if constexpr (MODE == 0) { sv = sp[u]; s2 = sv * sv; d2 = dv * dv; }
          else av = fabsf(dv);
#pragma unroll
          for (int o = 0; o < 4; ++o) {
            const float wk = g.w[wb + u - o];
            if constexpr (MODE == 0) {
              a0[o] += wk * sv; a1[o] += wk * dv;
              a2[o] += wk * s2; a3[o] += wk * d2;
            } else {
              a0[o] += wk * av;
            }
          }
        }
      }
      if constexpr (MODE == 0) {
        const int rb = hrow << 5;
#pragma unroll
        for (int o = 0; o < 4; ++o) {
          const int c = (cg << 2) + o;
          const int slot = rb + (c ^ ((c >> 3) & 3));
          *reinterpret_cast<float4*>(&hb[slot << 2]) =
              make_float4(a0[o], a1[o], a2[o], a3[o]);
        }
      } else {
        *reinterpret_cast<float4*>(&hb[(hrow << 5) + (cg << 2)]) =
            make_float4(a0[0], a0[1], a0[2], a0[3]);
      }
    }
  }
}

// Vertical pass. Thread owns col vc, output rows vr0..vr0+3.
template<int R, int WOFF, int MODE>
__device__ __forceinline__ void vpass(const GW& g, const float* __restrict__ hb,
                                      int vc, int vr0,
                                      float (&o0)[4], float (&o1)[4],
                                      float (&o2)[4], float (&o3)[4]) {
#pragma unroll
  for (int i = 0; i < 4; ++i) { o0[i] = o1[i] = o2[i] = o3[i] = 0.f; }
  const int fc = vc ^ ((vc >> 3) & 3);
#pragma unroll 2
  for (int jj = 0; jj < 2 * R + 4; ++jj) {
    const int r = vr0 + jj;
    float4 v = make_float4(0.f, 0.f, 0.f, 0.f);
    float vl = 0.f;
    if constexpr (MODE == 0)
      v = *reinterpret_cast<const float4*>(&hb[((r << 5) + fc) << 2]);
    else
      vl = hb[(r << 5) + vc];
    const int wb = WOFF + 8 + jj;   // weight index: wb - i (pads absorb overflow)
#pragma unroll
    for (int i = 0; i < 4; ++i) {
      const float wk = g.w[wb - i];
      if constexpr (MODE == 0) {
        o0[i] += wk * v.x; o1[i] += wk * v.y;
        o2[i] += wk * v.z; o3[i] += wk * v.w;
      } else {
        o0[i] += wk * vl;
      }
    }
  }
}

template<int R, int WOFF>
__device__ __forceinline__ void sweep4(const GW& g, int mult, bool doLM,
    const float* sS, const float* sD, float* hb, int t, int vc, int vr0,
    float (&PI)[4], float (&lM)[4]) {
  __syncthreads();
  hpass<R, WOFF, 0>(g, sS, sD, hb, t);
  __syncthreads();
  float os[4], od[4], os2[4], od2[4];
  vpass<R, WOFF, 0>(g, hb, vc, vr0, os, od, os2, od2);
#pragma unroll
  for (int i = 0; i < 4; ++i) {
    const float vs = os2[i] - os[i] * os[i];   // Var(x+y)
    const float vd = od2[i] - od[i] * od[i];   // Var(x-y)
    const float cs = (0.5f * (vs - vd) + kC2) / (0.5f * (vs + vd) + kC2);
    float p = cs;
    if (mult > 1) p *= cs;
    if (mult > 2) p *= cs;
    PI[i] *= p;
    if (doLM) {
      const float sa = os[i] * os[i], sb = od[i] * od[i];
      const float lc = (0.5f * (sa - sb) + kC1) / (0.5f * (sa + sb) + kC1);
      lM[i] = lc * lc * lc;
    }
  }
}

template<int R, int WOFF>
__device__ __forceinline__ void sweepL1(const GW& g,
    const float* sS, const float* sD, float* hb, int t, int vc, int vr0,
    float (&l1s)[4]) {
  __syncthreads();
  hpass<R, WOFF, 2>(g, sS, sD, hb, t);
  __syncthreads();
  float o0[4], o1[4], o2[4], o3[4];
  vpass<R, WOFF, 2>(g, hb, vc, vr0, o0, o1, o2, o3);
#pragma unroll
  for (int i = 0; i < 4; ++i) l1s[i] += o0[i];
}

__device__ __forceinline__ void load_tile(const float* __restrict__ p1,
                                          const float* __restrict__ p2,
                                          float* __restrict__ sS, float* __restrict__ sD,
                                          int t, int gx0, int gy0) {
#pragma unroll 1
  for (int e = 0; e < 4; ++e) {
    const int gidx = t + (e << 8);
    const int ly = gidx >> 4, lg = gidx & 15;
    const int gy = gy0 + ly;
    const int gx = gx0 + (lg << 2);
    float4 a = make_float4(0.f, 0.f, 0.f, 0.f);
    float4 b = make_float4(0.f, 0.f, 0.f, 0.f);
    if (gy >= 0 && gy < 512) {
      if (gx >= 0 && gx + 3 < 512) {
        a = *reinterpret_cast<const float4*>(&p1[(gy << 9) + gx]);
        b = *reinterpret_cast<const float4*>(&p2[(gy << 9) + gx]);
      } else {
        float* ap = reinterpret_cast<float*>(&a);
        float* bp = reinterpret_cast<float*>(&b);
#pragma unroll
        for (int u = 0; u < 4; ++u) {
          const int x = gx + u;
          if (x >= 0 && x < 512) { ap[u] = p1[(gy << 9) + x]; bp[u] = p2[(gy << 9) + x]; }
        }
      }
    }
    float4 s, d;
    s.x = a.x + b.x; s.y = a.y + b.y; s.z = a.z + b.z; s.w = a.w + b.w;
    d.x = a.x - b.x; d.y = a.y - b.y; d.z = a.z - b.z; d.w = a.w - b.w;
    const int off = (ly << 6) + ((lg ^ (ly & 7)) << 2);
    *reinterpret_cast<float4*>(&sS[off]) = s;
    *reinterpret_cast<float4*>(&sD[off]) = d;
  }
}

}  // namespace

extern "C" __global__ __launch_bounds__(256) void msssim_main(
    const float* __restrict__ img1, const float* __restrict__ img2,
    float* __restrict__ partial, GW g) {
  __shared__ __align__(16) float sS[4096];
  __shared__ __align__(16) float sD[4096];
  __shared__ __align__(16) float hb4[8192];   // MODE2 aliases the first 8 KB
  __shared__ float red[4];

  const int t = threadIdx.x;

  // XCD-contiguous swizzle: 2048 blocks / 8 XCDs -> XCD k owns batch image k.
  const int bid = (int)blockIdx.x + ((int)blockIdx.y << 4) + ((int)blockIdx.z << 8);
  const int swz = ((bid & 7) << 8) + (bid >> 3);
  const int bx = swz & 15, by = (swz >> 4) & 15, b = swz >> 8;

  const int gx0 = bx * 32 - 16;
  const int gy0 = by * 32 - 16;
  const int vc = t & 31;
  const int vr0 = (t >> 5) << 2;

  float PI[4] = {1.f, 1.f, 1.f, 1.f};
  float lM[4] = {0.f, 0.f, 0.f, 0.f};
  float l1s[4] = {0.f, 0.f, 0.f, 0.f};

  // Channel 0: cs(s0.5)^3 * cs(s1)^2 ; L1 blur s8
  {
    const float* p1 = img1 + (((size_t)b * 3 + 0) << 18);
    const float* p2 = img2 + (((size_t)b * 3 + 0) << 18);
    load_tile(p1, p2, sS, sD, t, gx0, gy0);
    sweep4<2, W05>(g, 3, false, sS, sD, hb4, t, vc, vr0, PI, lM);
    sweep4<5, W1>(g, 2, false, sS, sD, hb4, t, vc, vr0, PI, lM);
    sweepL1<16, W8>(g, sS, sD, hb4, t, vc, vr0, l1s);
  }
  // Channel 1: cs(s1)^1 * cs(s2)^3 * cs(s4)^1 ; L1 blur s8
  {
    const float* p1 = img1 + (((size_t)b * 3 + 1) << 18);
    const float* p2 = img2 + (((size_t)b * 3 + 1) << 18);
    load_tile(p1, p2, sS, sD, t, gx0, gy0);
    sweep4<5, W1>(g, 1, false, sS, sD, hb4, t, vc, vr0, PI, lM);
    sweep4<11, W2>(g, 3, false, sS, sD, hb4, t, vc, vr0, PI, lM);
    sweep4<16, W4>(g, 1, false, sS, sD, hb4, t, vc, vr0, PI, lM);
    sweepL1<16, W8>(g, sS, sD, hb4, t, vc, vr0, l1s);
  }
  // Channel 2: cs(s4)^2 * cs(s8)^3 + lM(s8) ; L1 blur s8
  {
    const float* p1 = img1 + (((size_t)b * 3 + 2) << 18);
    const float* p2 = img2 + (((size_t)b * 3 + 2) << 18);
    load_tile(p1, p2, sS, sD, t, gx0, gy0);
    sweep4<16, W4>(g, 2, false, sS, sD, hb4, t, vc, vr0, PI, lM);
    sweep4<16, W8>(g, 3, true, sS, sD, hb4, t, vc, vr0, PI, lM);
    sweepL1<16, W8>(g, sS, sD, hb4, t, vc, vr0, l1s);
  }

  float s = 0.f;
#pragma unroll
  for (int i = 0; i < 4; ++i)
    s += 0.025f * (1.f - lM[i] * PI[i]) + 0.975f * (l1s[i] * (1.f / 3.f));

#pragma unroll
  for (int off = 32; off >= 1; off >>= 1) s += __shfl_down(s, off, 64);
  if ((t & 63) == 0) red[t >> 6] = s;
  __syncthreads();
  if (t == 0) partial[swz] = red[0] + red[1] + red[2] + red[3];
}

extern "C" __global__ __launch_bounds__(256) void msssim_reduce(
    const float* __restrict__ partial, float* __restrict__ out, int n) {
  __shared__ float red[4];
  float s = 0.f;
  for (int i = threadIdx.x; i < n; i += 256) s += partial[i];
#pragma unroll
  for (int off = 32; off >= 1; off >>= 1) s += __shfl_down(s, off, 64);
  if ((threadIdx.x & 63) == 0) red[threadIdx.x >> 6] = s;
  __syncthreads();
  if (threadIdx.x == 0) {
    out[0] = (red[0] + red[1] + red[2] + red[3]) * (200.0f / 2097152.0f);
  }
}

extern "C" void kernel_launch(void* const* d_in, const int* in_sizes, int n_in,
                              void* d_out, int out_size, void* d_ws, size_t ws_size,
                              hipStream_t stream) {
  const float* img1 = (const float*)d_in[0];
  const float* img2 = (const float*)d_in[1];
  float* out = (float*)d_out;
  float* partial = (float*)d_ws;  // 2048 floats

  // Host-side padded weight tables (double-precision normalize, then cast).
  GW g;
  {
    const double sig[5] = {0.5, 1.0, 2.0, 4.0, 8.0};
    const int R[5] = {2, 5, 11, 16, 16};
    const int off[5] = {W05, W1, W2, W4, W8};
    for (int i = 0; i < 5; ++i) {
      double tmp[17];
      double sum = 0.0;
      for (int k = 0; k <= R[i]; ++k) {
        tmp[k] = exp(-(double)(k * k) / (2.0 * sig[i] * sig[i]));
        sum += (k ? 2.0 : 1.0) * tmp[k];
      }
      const int len = 2 * R[i] + 17;
      for (int m = 0; m < len; ++m) {
        int d = m - 8 - R[i];
        if (d < 0) d = -d;
        g.w[off[i] + m] = (m >= 8 && m <= 8 + 2 * R[i]) ? (float)(tmp[d] / sum) : 0.0f;
      }
    }
  }

  dim3 grid(16, 16, 8);
  msssim_main<<<grid, dim3(256), 0, stream>>>(img1, img2, partial, g);
  msssim_reduce<<<1, dim3(256), 0, stream>>>(partial, out, 2048);
}